// Round 2
// baseline (453.089 us; speedup 1.0000x reference)
//
#include <hip/hip_runtime.h>

// Sparsemax over rows: x is [16384, 4096] fp32, out same shape fp32.
// One WAVE (64 lanes) per row: 64 floats/lane register-resident, no LDS,
// no __syncthreads. tau via candidate lower-bound (tau* >= rowmax-1) +
// Michelot fixed-point iteration on register data, shuffle reductions only.

constexpr int COLS = 4096;
constexpr int TPB  = 256;              // 4 waves -> 4 rows per block
constexpr int RPB  = TPB / 64;

using f32x4 = __attribute__((ext_vector_type(4))) float;

__device__ __forceinline__ float wred_sum(float v) {
    #pragma unroll
    for (int m = 32; m; m >>= 1) v += __shfl_xor(v, m, 64);
    return v;
}
__device__ __forceinline__ float wred_max(float v) {
    #pragma unroll
    for (int m = 32; m; m >>= 1) v = fmaxf(v, __shfl_xor(v, m, 64));
    return v;
}

__global__ __launch_bounds__(TPB, 4) void sparsemax_kernel(const float* __restrict__ x,
                                                           float* __restrict__ out) {
    const int lane = threadIdx.x & 63;
    const int row  = blockIdx.x * RPB + (threadIdx.x >> 6);

    const f32x4* __restrict__ xr = reinterpret_cast<const f32x4*>(x + (size_t)row * COLS);
    f32x4* __restrict__ outr     = reinterpret_cast<f32x4*>(out + (size_t)row * COLS);

    // 16 independent coalesced 16B loads per lane (64 floats/lane).
    f32x4 v[16];
    #pragma unroll
    for (int j = 0; j < 16; ++j) v[j] = xr[lane + 64 * j];

    // ---- wave max ----
    float mx = v[0].x;
    #pragma unroll
    for (int j = 0; j < 16; ++j) {
        mx = fmaxf(mx, fmaxf(fmaxf(v[j].x, v[j].y), fmaxf(v[j].z, v[j].w)));
    }
    mx = wred_max(mx);
    const float lb = mx - 1.0f;   // support subset of {x > lb}

    // ---- initial candidate set S0 = {x > lb}: sum & count ----
    float s = 0.f, cnt = 0.f;
    #pragma unroll
    for (int j = 0; j < 16; ++j) {
        s   += (v[j].x > lb) ? v[j].x : 0.f;  cnt += (v[j].x > lb) ? 1.f : 0.f;
        s   += (v[j].y > lb) ? v[j].y : 0.f;  cnt += (v[j].y > lb) ? 1.f : 0.f;
        s   += (v[j].z > lb) ? v[j].z : 0.f;  cnt += (v[j].z > lb) ? 1.f : 0.f;
        s   += (v[j].w > lb) ? v[j].w : 0.f;  cnt += (v[j].w > lb) ? 1.f : 0.f;
    }
    s = wred_sum(s); cnt = wred_sum(cnt);
    float t = (s - 1.f) / cnt;    // tau_0 <= tau*, Michelot ascends to tau*

    // ---- Michelot fixed point: t <- (sum_{x>t} x - 1)/|{x>t}| until stable ----
    for (int it = 0; it < 24; ++it) {
        s = 0.f; cnt = 0.f;
        #pragma unroll
        for (int j = 0; j < 16; ++j) {
            s   += (v[j].x > t) ? v[j].x : 0.f;  cnt += (v[j].x > t) ? 1.f : 0.f;
            s   += (v[j].y > t) ? v[j].y : 0.f;  cnt += (v[j].y > t) ? 1.f : 0.f;
            s   += (v[j].z > t) ? v[j].z : 0.f;  cnt += (v[j].z > t) ? 1.f : 0.f;
            s   += (v[j].w > t) ? v[j].w : 0.f;  cnt += (v[j].w > t) ? 1.f : 0.f;
        }
        s = wred_sum(s); cnt = wred_sum(cnt);   // cnt >= 1 always (max > tau)
        float nt = (s - 1.f) / cnt;
        if (nt == t) break;       // wave-uniform: set stabilized -> exact tau
        t = nt;
    }

    // ---- epilogue: out = max(x - t, 0), nontemporal dwordx4 stores ----
    #pragma unroll
    for (int j = 0; j < 16; ++j) {
        f32x4 r;
        r.x = fmaxf(v[j].x - t, 0.f);
        r.y = fmaxf(v[j].y - t, 0.f);
        r.z = fmaxf(v[j].z - t, 0.f);
        r.w = fmaxf(v[j].w - t, 0.f);
        __builtin_nontemporal_store(r, &outr[lane + 64 * j]);
    }
}

extern "C" void kernel_launch(void* const* d_in, const int* in_sizes, int n_in,
                              void* d_out, int out_size, void* d_ws, size_t ws_size,
                              hipStream_t stream) {
    const float* x = (const float*)d_in[0];
    float*       o = (float*)d_out;
    const int rows = in_sizes[0] / COLS;     // 16384
    sparsemax_kernel<<<rows / RPB, TPB, 0, stream>>>(x, o);
}

// Round 3
// 449.553 us; speedup vs baseline: 1.0079x; 1.0079x over previous
//
#include <hip/hip_runtime.h>

// Sparsemax over rows: x is [16384, 4096] fp32, out same shape fp32.
// One WAVE per row, 64 floats/lane PINNED in VGPRs (asm barrier prevents the
// compiler from rematerializing them via global re-loads — R2's failure mode:
// VGPR_Count=52 proved v[] was re-read from L2/L3 every Michelot pass).
// tau: candidates {x > rowmax-1} (~14/row for N(0,1)) compacted to per-wave
// LDS, Michelot fixed-point on that tiny list. 3 register passes total.

constexpr int COLS = 4096;
constexpr int TPB  = 256;        // 4 waves -> 4 rows per block
constexpr int RPB  = TPB / 64;
constexpr int CAP  = 256;        // per-wave candidate capacity (expect ~14)

using f32x4 = __attribute__((ext_vector_type(4))) float;

__device__ __forceinline__ float wred_sum(float v) {
    #pragma unroll
    for (int m = 32; m; m >>= 1) v += __shfl_xor(v, m, 64);
    return v;
}
__device__ __forceinline__ float wred_max(float v) {
    #pragma unroll
    for (int m = 32; m; m >>= 1) v = fmaxf(v, __shfl_xor(v, m, 64));
    return v;
}

__global__ __launch_bounds__(TPB, 4) void sparsemax_kernel(const float* __restrict__ x,
                                                           float* __restrict__ out) {
    const int lane = threadIdx.x & 63;
    const int w    = threadIdx.x >> 6;
    const int row  = blockIdx.x * RPB + w;

    const f32x4* __restrict__ xr = reinterpret_cast<const f32x4*>(x + (size_t)row * COLS);
    f32x4* __restrict__ outr     = reinterpret_cast<f32x4*>(out + (size_t)row * COLS);

    // 16 independent coalesced 16B loads -> 64 floats/lane.
    float v[64];
    #pragma unroll
    for (int j = 0; j < 16; ++j) {
        f32x4 t4 = xr[lane + 64 * j];
        v[4 * j + 0] = t4.x; v[4 * j + 1] = t4.y;
        v[4 * j + 2] = t4.z; v[4 * j + 3] = t4.w;
    }
    // Pin every value into a VGPR. Opaque asm output cannot be rematerialized,
    // so no global re-loads are possible downstream.
    #pragma unroll
    for (int j = 0; j < 64; ++j) asm volatile("" : "+v"(v[j]));

    __shared__ float cand[RPB][CAP];
    __shared__ int   ccnt[RPB];

    // ---- pass 1: wave max ----
    float mx = v[0];
    #pragma unroll
    for (int j = 1; j < 64; ++j) mx = fmaxf(mx, v[j]);
    mx = wred_max(mx);
    const float lb = mx - 1.0f;    // tau* >= rowmax-1 -> support subset of {x > lb}

    if (lane == 0) ccnt[w] = 0;
    __syncthreads();

    // ---- pass 2: compact candidates {x > lb} into per-wave LDS list ----
    #pragma unroll
    for (int j = 0; j < 64; ++j) {
        if (v[j] > lb) {
            int idx = atomicAdd(&ccnt[w], 1);
            if (idx < CAP) cand[w][idx] = v[j];
        }
    }
    __syncthreads();
    const int nc = ccnt[w];

    // ---- Michelot fixed point on the candidate list (wave-uniform) ----
    float t;
    if (nc <= CAP) {
        float s = 0.f, cnt = 0.f;
        for (int j = lane; j < nc; j += 64) { s += cand[w][j]; cnt += 1.f; }
        s = wred_sum(s); cnt = wred_sum(cnt);
        t = (s - 1.f) / cnt;                    // tau_0 <= tau*, ascends to tau*
        for (int it = 0; it < CAP + 2; ++it) {
            s = 0.f; cnt = 0.f;
            for (int j = lane; j < nc; j += 64) {
                float cv = cand[w][j];
                if (cv > t) { s += cv; cnt += 1.f; }
            }
            s = wred_sum(s); cnt = wred_sum(cnt);  // cnt >= 1 (rowmax > tau)
            float nt = (s - 1.f) / cnt;
            if (nt == t) break;                 // set stabilized -> exact
            t = nt;
        }
    } else {
        // Pathological fallback (never taken for N(0,1) rows): Michelot over regs.
        float s = 0.f, cnt = 0.f;
        #pragma unroll
        for (int j = 0; j < 64; ++j) if (v[j] > lb) { s += v[j]; cnt += 1.f; }
        s = wred_sum(s); cnt = wred_sum(cnt);
        t = (s - 1.f) / cnt;
        for (int it = 0; it < 256; ++it) {
            s = 0.f; cnt = 0.f;
            #pragma unroll
            for (int j = 0; j < 64; ++j) if (v[j] > t) { s += v[j]; cnt += 1.f; }
            s = wred_sum(s); cnt = wred_sum(cnt);
            float nt = (s - 1.f) / cnt;
            if (nt == t) break;
            t = nt;
        }
    }

    // ---- pass 3: epilogue, nontemporal dwordx4 stores ----
    #pragma unroll
    for (int j = 0; j < 16; ++j) {
        f32x4 r;
        r.x = fmaxf(v[4 * j + 0] - t, 0.f);
        r.y = fmaxf(v[4 * j + 1] - t, 0.f);
        r.z = fmaxf(v[4 * j + 2] - t, 0.f);
        r.w = fmaxf(v[4 * j + 3] - t, 0.f);
        __builtin_nontemporal_store(r, &outr[lane + 64 * j]);
    }
}

extern "C" void kernel_launch(void* const* d_in, const int* in_sizes, int n_in,
                              void* d_out, int out_size, void* d_ws, size_t ws_size,
                              hipStream_t stream) {
    const float* x = (const float*)d_in[0];
    float*       o = (float*)d_out;
    const int rows = in_sizes[0] / COLS;      // 16384
    sparsemax_kernel<<<rows / RPB, TPB, 0, stream>>>(x, o);
}

// Round 4
// 427.753 us; speedup vs baseline: 1.0592x; 1.0510x over previous
//
#include <hip/hip_runtime.h>

// Sparsemax over rows: x [16384,4096] fp32 -> out same shape.
// Block-per-row (256 thr, 16 vals/thread) at MAX occupancy:
// __launch_bounds__(256,8) -> ~50 VGPR -> 8 blocks/CU = 32 waves/CU, so some
// block is always issuing loads/stores (R3's wave-per-row sat at 34% occ,
// 2.4 TB/s). Plain stores (R3's nt stores A/B'd out).
// tau: support subset of {x > rowmax-1} (~14/row for N(0,1)); compact to LDS,
// Michelot fixed point on wave 0 with candidates in registers (1 LDS read).

constexpr int COLS = 4096;
constexpr int TPB  = 256;
constexpr int CAP  = 256;

using f32x4 = __attribute__((ext_vector_type(4))) float;

__device__ __forceinline__ float wred_sum(float v) {
    #pragma unroll
    for (int m = 32; m; m >>= 1) v += __shfl_xor(v, m, 64);
    return v;
}
__device__ __forceinline__ float wred_max(float v) {
    #pragma unroll
    for (int m = 32; m; m >>= 1) v = fmaxf(v, __shfl_xor(v, m, 64));
    return v;
}

__global__ __launch_bounds__(TPB, 8) void sparsemax_kernel(const float* __restrict__ x,
                                                           float* __restrict__ out) {
    const int row  = blockIdx.x;
    const int tid  = threadIdx.x;
    const int lane = tid & 63;
    const int wv   = tid >> 6;

    const f32x4* __restrict__ xr  = reinterpret_cast<const f32x4*>(x + (size_t)row * COLS);
    f32x4* __restrict__       orr = reinterpret_cast<f32x4*>(out + (size_t)row * COLS);

    // 4 independent coalesced 16B loads -> 16 floats/thread.
    f32x4 q0 = xr[tid], q1 = xr[tid + TPB], q2 = xr[tid + 2 * TPB], q3 = xr[tid + 3 * TPB];
    float v[16] = {q0.x, q0.y, q0.z, q0.w, q1.x, q1.y, q1.z, q1.w,
                   q2.x, q2.y, q2.z, q2.w, q3.x, q3.y, q3.z, q3.w};
    #pragma unroll
    for (int j = 0; j < 16; ++j) asm volatile("" : "+v"(v[j]));  // keep register-resident

    __shared__ float redm[4], reds[4], redc[4];
    __shared__ float cand[CAP];
    __shared__ int   ccount;
    __shared__ float tau_sh;

    // ---- block max ----
    float mx = v[0];
    #pragma unroll
    for (int j = 1; j < 16; ++j) mx = fmaxf(mx, v[j]);
    mx = wred_max(mx);
    if (lane == 0) redm[wv] = mx;
    if (tid == 0) ccount = 0;
    __syncthreads();
    const float rowmax = fmaxf(fmaxf(redm[0], redm[1]), fmaxf(redm[2], redm[3]));
    const float lb = rowmax - 1.0f;   // tau* >= rowmax-1 -> support subset of {x > lb}

    // ---- compact candidates {x > lb} into LDS ----
    #pragma unroll
    for (int j = 0; j < 16; ++j) {
        if (v[j] > lb) {
            int idx = atomicAdd(&ccount, 1);
            if (idx < CAP) cand[idx] = v[j];
        }
    }
    __syncthreads();
    const int nc = ccount;            // block-uniform

    float tau;
    if (nc <= CAP) {
        if (wv == 0) {
            float t;
            if (nc <= 64) {
                // One LDS read; Michelot entirely in registers/shuffles.
                float cv  = (lane < nc) ? cand[lane] : 0.f;
                float s0  = wred_sum(cv);
                t = (s0 - 1.f) / (float)nc;          // tau_0 <= tau*, ascends
                float cvm = (lane < nc) ? cv : -3.0e38f;
                for (int it = 0; it < 66; ++it) {
                    float si = (cvm > t) ? cvm : 0.f;
                    float ci = (cvm > t) ? 1.f : 0.f;
                    si = wred_sum(si); ci = wred_sum(ci);   // ci >= 1 (rowmax > t)
                    float nt = (si - 1.f) / ci;
                    if (nt == t) break;               // set stabilized -> exact
                    t = nt;
                }
            } else {
                // 64 < nc <= CAP: strided LDS Michelot.
                float s = 0.f, cnt = 0.f;
                for (int j = lane; j < nc; j += 64) { s += cand[j]; cnt += 1.f; }
                s = wred_sum(s); cnt = wred_sum(cnt);
                t = (s - 1.f) / cnt;
                for (int it = 0; it < CAP + 2; ++it) {
                    s = 0.f; cnt = 0.f;
                    for (int j = lane; j < nc; j += 64) {
                        float cv = cand[j];
                        if (cv > t) { s += cv; cnt += 1.f; }
                    }
                    s = wred_sum(s); cnt = wred_sum(cnt);
                    float nt = (s - 1.f) / cnt;
                    if (nt == t) break;
                    t = nt;
                }
            }
            if (lane == 0) tau_sh = t;
        }
        __syncthreads();
        tau = tau_sh;
    } else {
        // Pathological fallback (>256 candidates within 1.0 of rowmax): block
        // binary search over registers, then exact final step.
        float lo = lb, hi = rowmax;
        for (int it = 0; it < 40; ++it) {
            float mid = 0.5f * (lo + hi);
            float s = 0.f;
            #pragma unroll
            for (int j = 0; j < 16; ++j) s += fmaxf(v[j] - mid, 0.f);
            s = wred_sum(s);
            if (lane == 0) reds[wv] = s;
            __syncthreads();
            s = reds[0] + reds[1] + reds[2] + reds[3];
            __syncthreads();
            if (s > 1.f) lo = mid; else hi = mid;
        }
        float s = 0.f, cnt = 0.f;
        #pragma unroll
        for (int j = 0; j < 16; ++j) if (v[j] > lo) { s += v[j]; cnt += 1.f; }
        s = wred_sum(s); cnt = wred_sum(cnt);
        if (lane == 0) { reds[wv] = s; redc[wv] = cnt; }
        __syncthreads();
        s   = reds[0] + reds[1] + reds[2] + reds[3];
        cnt = redc[0] + redc[1] + redc[2] + redc[3];
        tau = (s - 1.f) / cnt;
    }

    // ---- epilogue: out = max(x - tau, 0), plain dwordx4 stores ----
    f32x4 r0, r1, r2, r3;
    r0.x = fmaxf(v[0]  - tau, 0.f); r0.y = fmaxf(v[1]  - tau, 0.f);
    r0.z = fmaxf(v[2]  - tau, 0.f); r0.w = fmaxf(v[3]  - tau, 0.f);
    r1.x = fmaxf(v[4]  - tau, 0.f); r1.y = fmaxf(v[5]  - tau, 0.f);
    r1.z = fmaxf(v[6]  - tau, 0.f); r1.w = fmaxf(v[7]  - tau, 0.f);
    r2.x = fmaxf(v[8]  - tau, 0.f); r2.y = fmaxf(v[9]  - tau, 0.f);
    r2.z = fmaxf(v[10] - tau, 0.f); r2.w = fmaxf(v[11] - tau, 0.f);
    r3.x = fmaxf(v[12] - tau, 0.f); r3.y = fmaxf(v[13] - tau, 0.f);
    r3.z = fmaxf(v[14] - tau, 0.f); r3.w = fmaxf(v[15] - tau, 0.f);
    orr[tid]           = r0;
    orr[tid + TPB]     = r1;
    orr[tid + 2 * TPB] = r2;
    orr[tid + 3 * TPB] = r3;
}

extern "C" void kernel_launch(void* const* d_in, const int* in_sizes, int n_in,
                              void* d_out, int out_size, void* d_ws, size_t ws_size,
                              hipStream_t stream) {
    const float* x = (const float*)d_in[0];
    float*       o = (float*)d_out;
    const int rows = in_sizes[0] / COLS;   // 16384
    sparsemax_kernel<<<rows, TPB, 0, stream>>>(x, o);
}